// Round 2
// baseline (18.324 us; speedup 1.0000x reference)
//
#include <hip/hip_runtime.h>

// BagOfWords: out[b][v] = count of token v in docs[b][:] / SEQ
// docs: int32 [256, 2048], out: float32 [256, 32000]

#define VOCAB 32000
#define BATCH 256
#define SEQ   2048
#define NCHUNK 8
#define CHUNK (VOCAB / NCHUNK)   // 4000 bins -> 16 KB LDS per workgroup
#define BLK   256

__global__ __launch_bounds__(BLK) void bow_hist_kernel(
    const int* __restrict__ docs, float* __restrict__ out) {
    __shared__ unsigned int bins[CHUNK];

    const int wg   = blockIdx.x;          // 0 .. BATCH*NCHUNK-1
    const int b    = wg >> 3;             // row index
    const int c    = wg & (NCHUNK - 1);   // vocab chunk
    const int base = c * CHUNK;
    const int tid  = threadIdx.x;

    // Hoist the token loads so HBM/L2 latency hides under the LDS zeroing.
    const int4* row4 = reinterpret_cast<const int4*>(docs + (size_t)b * SEQ);
    int4 t0 = row4[tid];            // SEQ/4 = 512 int4; 2 per thread
    int4 t1 = row4[BLK + tid];

    // 1) zero the LDS histogram chunk (vectorized, ds_write_b128)
    uint4* bins4 = reinterpret_cast<uint4*>(bins);
    #pragma unroll
    for (int i = tid; i < CHUNK / 4; i += BLK) {   // 1000 uint4
        bins4[i] = make_uint4(0u, 0u, 0u, 0u);
    }
    __syncthreads();

    // 2) scatter this wave's 8 tokens into the LDS chunk
    int r;
    r = t0.x - base; if ((unsigned)r < (unsigned)CHUNK) atomicAdd(&bins[r], 1u);
    r = t0.y - base; if ((unsigned)r < (unsigned)CHUNK) atomicAdd(&bins[r], 1u);
    r = t0.z - base; if ((unsigned)r < (unsigned)CHUNK) atomicAdd(&bins[r], 1u);
    r = t0.w - base; if ((unsigned)r < (unsigned)CHUNK) atomicAdd(&bins[r], 1u);
    r = t1.x - base; if ((unsigned)r < (unsigned)CHUNK) atomicAdd(&bins[r], 1u);
    r = t1.y - base; if ((unsigned)r < (unsigned)CHUNK) atomicAdd(&bins[r], 1u);
    r = t1.z - base; if ((unsigned)r < (unsigned)CHUNK) atomicAdd(&bins[r], 1u);
    r = t1.w - base; if ((unsigned)r < (unsigned)CHUNK) atomicAdd(&bins[r], 1u);
    __syncthreads();

    // 3) stream the chunk out, normalized; ds_read_b128 + coalesced float4 store
    float* orow = out + (size_t)b * VOCAB + base;
    const float inv = 1.0f / (float)SEQ;   // exact power of two
    #pragma unroll
    for (int i = tid; i < CHUNK / 4; i += BLK) {   // 1000 float4
        uint4 u = bins4[i];
        float4 v;
        v.x = (float)u.x * inv;
        v.y = (float)u.y * inv;
        v.z = (float)u.z * inv;
        v.w = (float)u.w * inv;
        reinterpret_cast<float4*>(orow)[i] = v;
    }
}

extern "C" void kernel_launch(void* const* d_in, const int* in_sizes, int n_in,
                              void* d_out, int out_size, void* d_ws, size_t ws_size,
                              hipStream_t stream) {
    const int* docs = (const int*)d_in[0];
    float* out = (float*)d_out;
    dim3 grid(BATCH * NCHUNK);
    dim3 block(BLK);
    bow_hist_kernel<<<grid, block, 0, stream>>>(docs, out);
}

// Round 3
// 17.600 us; speedup vs baseline: 1.0412x; 1.0412x over previous
//
#include <hip/hip_runtime.h>

// BagOfWords: out[b][v] = count of token v in docs[b][:] / SEQ
// docs: int32 [256, 2048], out: float32 [256, 32000]
//
// Design: 1 WG per row, full 32000-bin histogram in 128 KB LDS (fits in
// gfx950's 160 KB/CU). 256 WGs = exactly 1 per CU. Every token loaded
// exactly once, no vocab-range filtering, output streamed contiguously.

#define VOCAB 32000
#define BATCH 256
#define SEQ   2048
#define BLK   1024               // 16 waves

__global__ __launch_bounds__(BLK) void bow_hist_kernel(
    const int* __restrict__ docs, float* __restrict__ out) {
    __shared__ unsigned int bins[VOCAB];   // 128 KB

    const int b   = blockIdx.x;
    const int tid = threadIdx.x;

    // Hoist this thread's 2 tokens so the global-load latency hides
    // under the LDS zeroing phase. Coalesced int2 (8 B/lane).
    const int2* row2 = reinterpret_cast<const int2*>(docs + (size_t)b * SEQ);
    int2 t = row2[tid];                    // SEQ/2 = 1024 int2, one per thread

    // 1) zero the histogram (vectorized ds_write_b128: 8000 uint4 total)
    uint4* bins4 = reinterpret_cast<uint4*>(bins);
    #pragma unroll
    for (int i = tid; i < VOCAB / 4; i += BLK) {   // 7-8 iters/thread
        bins4[i] = make_uint4(0u, 0u, 0u, 0u);
    }
    __syncthreads();

    // 2) scatter: 2 LDS atomics per thread, random over 32000 bins
    atomicAdd(&bins[t.x], 1u);
    atomicAdd(&bins[t.y], 1u);
    __syncthreads();

    // 3) stream out, normalized; ds_read_b128 + coalesced dwordx4 stores
    float* orow = out + (size_t)b * VOCAB;
    const float inv = 1.0f / (float)SEQ;   // exact power of two
    #pragma unroll
    for (int i = tid; i < VOCAB / 4; i += BLK) {
        uint4 u = bins4[i];
        float4 v;
        v.x = (float)u.x * inv;
        v.y = (float)u.y * inv;
        v.z = (float)u.z * inv;
        v.w = (float)u.w * inv;
        reinterpret_cast<float4*>(orow)[i] = v;
    }
}

extern "C" void kernel_launch(void* const* d_in, const int* in_sizes, int n_in,
                              void* d_out, int out_size, void* d_ws, size_t ws_size,
                              hipStream_t stream) {
    const int* docs = (const int*)d_in[0];
    float* out = (float*)d_out;
    bow_hist_kernel<<<dim3(BATCH), dim3(BLK), 0, stream>>>(docs, out);
}

// Round 4
// 11.826 us; speedup vs baseline: 1.5495x; 1.4882x over previous
//
#include <hip/hip_runtime.h>

// BagOfWords: out[b][v] = count of token v in docs[b][:] / SEQ
// docs: int32 [256, 2048], out: float32 [256, 32000]
//
// Structure (R4): 4 vocab chunks x 512-thread blocks, 32 KB LDS each.
// 1024 WGs -> 4 blocks/CU (LDS-full), 8 waves/block -> 32 waves/CU (max
// occupancy). Independent blocks overlap their zero/scatter/store phases
// on each CU; loads issued in the scan phase (R1-style, the fastest).

#define VOCAB 32000
#define BATCH 256
#define SEQ   2048
#define NCHUNK 4
#define CHUNK (VOCAB / NCHUNK)   // 8000 bins -> 32 KB LDS
#define BLK   512

__global__ __launch_bounds__(BLK) void bow_hist_kernel(
    const int* __restrict__ docs, float* __restrict__ out) {
    __shared__ unsigned int bins[CHUNK];

    const int wg   = blockIdx.x;          // 0 .. BATCH*NCHUNK-1
    const int b    = wg >> 2;             // row index
    const int c    = wg & (NCHUNK - 1);   // vocab chunk
    const int base = c * CHUNK;
    const int tid  = threadIdx.x;

    // 1) zero the LDS histogram chunk (ds_write_b128; 2000 uint4)
    uint4* bins4 = reinterpret_cast<uint4*>(bins);
    for (int i = tid; i < CHUNK / 4; i += BLK) {   // ~4 iters
        bins4[i] = make_uint4(0u, 0u, 0u, 0u);
    }
    __syncthreads();

    // 2) scan the row: 512 int4 covers all 2048 tokens (1 per thread)
    const int4* row4 = reinterpret_cast<const int4*>(docs + (size_t)b * SEQ);
    int4 t = row4[tid];
    int r;
    r = t.x - base; if ((unsigned)r < (unsigned)CHUNK) atomicAdd(&bins[r], 1u);
    r = t.y - base; if ((unsigned)r < (unsigned)CHUNK) atomicAdd(&bins[r], 1u);
    r = t.z - base; if ((unsigned)r < (unsigned)CHUNK) atomicAdd(&bins[r], 1u);
    r = t.w - base; if ((unsigned)r < (unsigned)CHUNK) atomicAdd(&bins[r], 1u);
    __syncthreads();

    // 3) stream the chunk out, normalized (ds_read_b128 + dwordx4 stores)
    float* orow = out + (size_t)b * VOCAB + base;
    const float inv = 1.0f / (float)SEQ;   // exact power of two
    for (int i = tid; i < CHUNK / 4; i += BLK) {   // ~4 iters
        uint4 u = bins4[i];
        float4 v;
        v.x = (float)u.x * inv;
        v.y = (float)u.y * inv;
        v.z = (float)u.z * inv;
        v.w = (float)u.w * inv;
        reinterpret_cast<float4*>(orow)[i] = v;
    }
}

extern "C" void kernel_launch(void* const* d_in, const int* in_sizes, int n_in,
                              void* d_out, int out_size, void* d_ws, size_t ws_size,
                              hipStream_t stream) {
    const int* docs = (const int*)d_in[0];
    float* out = (float*)d_out;
    bow_hist_kernel<<<dim3(BATCH * NCHUNK), dim3(BLK), 0, stream>>>(docs, out);
}